// Round 1
// baseline (74.219 us; speedup 1.0000x reference)
//
#include <hip/hip_runtime.h>

// SqueezeExcitation: x[32,256,64,64] f32, W1[64,256], b1[64], W2[256,64], b2[256]
// y = x * hardsigmoid( relu( mean_hw(x) @ W1^T + b1 ) @ W2^T + b2 )
// (conv1x1 then spatial-mean == spatial-mean then matvec, since conv is linear)

#define SE_B  32
#define SE_C  256
#define SE_SQ 64
#define SE_HW 4096   // 64*64

// ---------------- Kernel 1: per-(b,c) spatial mean --------------------------
// one block (256 threads) per (b,c); 4096 floats = 1024 float4
__global__ __launch_bounds__(256) void se_mean_kernel(
    const float* __restrict__ x, float* __restrict__ m) {
    const int bc = blockIdx.x;                       // [0, B*C)
    const float4* xv = reinterpret_cast<const float4*>(x) + (size_t)bc * (SE_HW / 4);
    const int t = threadIdx.x;

    float s = 0.0f;
#pragma unroll
    for (int k = 0; k < 4; ++k) {
        float4 v = xv[t + 256 * k];
        s += (v.x + v.y) + (v.z + v.w);
    }
    // wave (64-lane) butterfly reduce
#pragma unroll
    for (int off = 32; off > 0; off >>= 1) s += __shfl_down(s, off);

    __shared__ float wsum[4];
    if ((t & 63) == 0) wsum[t >> 6] = s;
    __syncthreads();
    if (t == 0) m[bc] = (wsum[0] + wsum[1] + wsum[2] + wsum[3]) * (1.0f / SE_HW);
}

// ---------------- Kernel 2: gate = hardsigmoid(relu(m@W1^T+b1)@W2^T+b2) ----
// one block (256 threads) per batch element
__global__ __launch_bounds__(256) void se_gate_kernel(
    const float* __restrict__ m,
    const float* __restrict__ W1, const float* __restrict__ b1,
    const float* __restrict__ W2, const float* __restrict__ b2,
    float* __restrict__ gate) {
    const int b = blockIdx.x;
    const int t = threadIdx.x;

    __shared__ float sm[SE_C];
    __shared__ float ss[SE_SQ];

    sm[t] = m[b * SE_C + t];
    __syncthreads();

    if (t < SE_SQ) {
        float acc = b1[t];
        const float* w = W1 + t * SE_C;
#pragma unroll 8
        for (int c = 0; c < SE_C; ++c) acc = fmaf(w[c], sm[c], acc);
        ss[t] = fmaxf(acc, 0.0f);
    }
    __syncthreads();

    float acc = b2[t];
    const float* w = W2 + t * SE_SQ;
#pragma unroll 8
    for (int o = 0; o < SE_SQ; ++o) acc = fmaf(w[o], ss[o], acc);
    float g = acc * (1.0f / 6.0f) + 0.5f;
    g = fminf(fmaxf(g, 0.0f), 1.0f);
    gate[b * SE_C + t] = g;
}

// ---------------- Kernel 3: y = x * gate[b,c] -------------------------------
__global__ __launch_bounds__(256) void se_scale_kernel(
    const float* __restrict__ x, const float* __restrict__ gate,
    float* __restrict__ y) {
    const float4* xv = reinterpret_cast<const float4*>(x);
    float4* yv = reinterpret_cast<float4*>(y);
    const int total4 = SE_B * SE_C * SE_HW / 4;      // 8,388,608
    const int stride = gridDim.x * blockDim.x;
    for (int i = blockIdx.x * blockDim.x + threadIdx.x; i < total4; i += stride) {
        float g = gate[i >> 10];                     // 1024 float4 per (b,c)
        float4 v = xv[i];
        v.x *= g; v.y *= g; v.z *= g; v.w *= g;
        yv[i] = v;
    }
}

extern "C" void kernel_launch(void* const* d_in, const int* in_sizes, int n_in,
                              void* d_out, int out_size, void* d_ws, size_t ws_size,
                              hipStream_t stream) {
    const float* x  = (const float*)d_in[0];
    const float* W1 = (const float*)d_in[1];
    const float* b1 = (const float*)d_in[2];
    const float* W2 = (const float*)d_in[3];
    const float* b2 = (const float*)d_in[4];
    float* y = (float*)d_out;

    float* m    = (float*)d_ws;            // B*C = 8192 floats
    float* gate = m + SE_B * SE_C;         // B*C = 8192 floats

    se_mean_kernel<<<SE_B * SE_C, 256, 0, stream>>>(x, m);
    se_gate_kernel<<<SE_B, 256, 0, stream>>>(m, W1, b1, W2, b2, gate);
    se_scale_kernel<<<4096, 256, 0, stream>>>(x, gate, y);
}